// Round 11
// baseline (570.757 us; speedup 1.0000x reference)
//
#include <hip/hip_runtime.h>
#include <math.h>

// SPLFullLoss: x, ref f32[B=32, N=4096, D=512] -> scalar
//   a = -(1/(N*B)) * sum_rows Sxr/(max(sqrt(Sxx),eps)*max(sqrt(Srr),eps))  (rows along D)
//   b = -(1/(D*B)) * sum_cols Sxr/(max(sqrt(Sxx),eps)*max(sqrt(Srr),eps))  (cols along N)
// R11: R9 (atomic-free 3-pass) + VGPR-SAFE 2-deep pipeline: 2-row stages
// (32 VGPR/set, 2 sets) so ~8 KB/wave stays in flight under every compute
// phase WITHOUT spilling (R10's 4-row sets spilled: FETCH 638MB, WRITE 659MB).

#define BB 32
#define NN 4096
#define DD 512

static constexpr float EPS = 1e-12f;
static constexpr int BPB   = 64;          // blocks per batch
static constexpr int RPB   = NN / BPB;    // 64 rows per block
static constexpr int NWAVE = 4;           // 256 threads
static constexpr int RPW   = RPB / NWAVE; // 16 rows per wave
static constexpr int SUB   = 2;           // rows per pipeline stage
static constexpr int NST   = RPW / SUB;   // 8 stages

// ws layout (floats):
//   P[2048 blocks][1600]: [0,512) cxx | [512,1024) crr | [1024,1536) cxr | [1536] rowacc
//   ws2[256] at offset 2048*1600
static constexpr size_t S1     = 1600;
static constexpr size_t WS_W2  = (size_t)2048 * S1;
static constexpr size_t WS_FLOATS = WS_W2 + 256;

__global__ __launch_bounds__(256, 4) void spl_pass1(
    const float* __restrict__ x, const float* __restrict__ r, float* __restrict__ ws) {
  // col exchange buffer, half-D at a time: [wave][m][256] floats = 12 KiB
  __shared__ float lds[NWAVE][3][DD / 2];
  __shared__ float ldsrow[NWAVE];

  const int tid  = threadIdx.x;
  const int wave = tid >> 6;
  const int lane = tid & 63;
  const int blk  = blockIdx.x;
  const int b    = blk / BPB;
  const int bib  = blk % BPB;
  const int n0   = bib * RPB + wave * RPW;

  float cxx[8], crr[8], cxr[8];
#pragma unroll
  for (int j = 0; j < 8; ++j) { cxx[j] = 0.f; crr[j] = 0.f; cxr[j] = 0.f; }
  float rowacc = 0.f;

  const size_t base = (size_t)b * NN * DD + (size_t)n0 * DD;
  const float* xbase = x + base;
  const float* rbase = r + base;

  // issue the 8 loads of stage s (2 rows x 2 arrays x 2 float4)
  auto LOADS = [&](int s, float4 (&xd)[SUB][2], float4 (&rd)[SUB][2]) {
#pragma unroll
    for (int rr = 0; rr < SUB; ++rr) {
      const float4* xp = (const float4*)(xbase + (size_t)(s * SUB + rr) * DD);
      const float4* rp = (const float4*)(rbase + (size_t)(s * SUB + rr) * DD);
      xd[rr][0] = xp[lane];
      xd[rr][1] = xp[lane + 64];
      rd[rr][0] = rp[lane];
      rd[rr][1] = rp[lane + 64];
    }
  };

  // consume one register set: FMAs + 6 interleaved butterflies + row terms
  auto COMPUTE = [&](float4 (&xd)[SUB][2], float4 (&rd)[SUB][2]) {
    float sxx[SUB], srr[SUB], sxr[SUB];
#pragma unroll
    for (int rr = 0; rr < SUB; ++rr) {
      sxx[rr] = 0.f; srr[rr] = 0.f; sxr[rr] = 0.f;
#pragma unroll
      for (int k = 0; k < 2; ++k) {
        const float xs[4] = {xd[rr][k].x, xd[rr][k].y, xd[rr][k].z, xd[rr][k].w};
        const float rs[4] = {rd[rr][k].x, rd[rr][k].y, rd[rr][k].z, rd[rr][k].w};
#pragma unroll
        for (int j = 0; j < 4; ++j) {
          const float pxx = xs[j] * xs[j];
          const float prr = rs[j] * rs[j];
          const float pxr = xs[j] * rs[j];
          sxx[rr] += pxx; srr[rr] += prr; sxr[rr] += pxr;
          cxx[k * 4 + j] += pxx; crr[k * 4 + j] += prr; cxr[k * 4 + j] += pxr;
        }
      }
    }
#pragma unroll
    for (int off = 1; off < 64; off <<= 1) {
#pragma unroll
      for (int rr = 0; rr < SUB; ++rr) {
        sxx[rr] += __shfl_xor(sxx[rr], off, 64);
        srr[rr] += __shfl_xor(srr[rr], off, 64);
        sxr[rr] += __shfl_xor(sxr[rr], off, 64);
      }
    }
#pragma unroll
    for (int rr = 0; rr < SUB; ++rr) {
      const float nx = fmaxf(sqrtf(sxx[rr]), EPS);
      const float nr = fmaxf(sqrtf(srr[rr]), EPS);
      rowacc += sxr[rr] / (nx * nr);
    }
  };

  // ---- static 2-deep pipeline over 8 stages (named sets A, B; no dyn idx)
  float4 xA[SUB][2], rA[SUB][2], xB[SUB][2], rB[SUB][2];
  LOADS(0, xA, rA);
  LOADS(1, xB, rB);
  COMPUTE(xA, rA); LOADS(2, xA, rA);   // B in flight during COMPUTE(A)
  COMPUTE(xB, rB); LOADS(3, xB, rB);
  COMPUTE(xA, rA); LOADS(4, xA, rA);
  COMPUTE(xB, rB); LOADS(5, xB, rB);
  COMPUTE(xA, rA); LOADS(6, xA, rA);
  COMPUTE(xB, rB); LOADS(7, xB, rB);
  COMPUTE(xA, rA);
  COMPUTE(xB, rB);

  if (lane == 0) ldsrow[wave] = rowacc;

  float* P = ws + (size_t)blk * S1;

  // ---- column exchange, half 0: d in [0,256), reg slots 0..3
  __syncthreads();
  {
    float4* cb = (float4*)&lds[0][0][0];  // [wave*3+m][64] float4s
#pragma unroll
    for (int m = 0; m < 3; ++m) {
      const float* c = (m == 0) ? cxx : (m == 1) ? crr : cxr;
      cb[(wave * 3 + m) * 64 + lane] = make_float4(c[0], c[1], c[2], c[3]);
    }
  }
  __syncthreads();
  for (int i = tid; i < 768; i += 256) {
    const int m = i >> 8;
    const int d = i & 255;
    P[m * 512 + d] = lds[0][m][d] + lds[1][m][d] + lds[2][m][d] + lds[3][m][d];
  }

  // ---- column exchange, half 1: d in [256,512), reg slots 4..7
  __syncthreads();
  {
    float4* cb = (float4*)&lds[0][0][0];
#pragma unroll
    for (int m = 0; m < 3; ++m) {
      const float* c = (m == 0) ? cxx : (m == 1) ? crr : cxr;
      cb[(wave * 3 + m) * 64 + lane] = make_float4(c[4], c[5], c[6], c[7]);
    }
  }
  __syncthreads();
  for (int i = tid; i < 768; i += 256) {
    const int m = i >> 8;
    const int d = i & 255;
    P[m * 512 + 256 + d] = lds[0][m][d] + lds[1][m][d] + lds[2][m][d] + lds[3][m][d];
  }

  if (tid == 0) {
    P[1536] = ldsrow[0] + ldsrow[1] + ldsrow[2] + ldsrow[3];
  }
}

// 256 blocks x 64 threads: block g handles batch b=g/8, d-slice (g%8)*64..+64.
__global__ __launch_bounds__(64, 8) void spl_pass2(const float* __restrict__ ws,
                                                   float* __restrict__ ws2) {
  const int lane = threadIdx.x;
  const int g    = blockIdx.x;
  const int b    = g >> 3;
  const int d    = (g & 7) * 64 + lane;

  float sxx = 0.f, srr = 0.f, sxr = 0.f;
  const float* Pb = ws + (size_t)(b * BPB) * S1;
#pragma unroll 4
  for (int bib = 0; bib < BPB; ++bib) {
    const float* P = Pb + (size_t)bib * S1;
    sxx += P[d];
    srr += P[512 + d];
    sxr += P[1024 + d];
  }
  const float nx = fmaxf(sqrtf(sxx), EPS);
  const float nr = fmaxf(sqrtf(srr), EPS);
  float term = sxr / (nx * nr);   // per-d column term
#pragma unroll
  for (int off = 1; off < 64; off <<= 1) term += __shfl_xor(term, off, 64);

  float rterm = 0.f;
  if ((g & 7) == 0) {
    float rv = Pb[(size_t)lane * S1 + 1536];  // one row-partial per lane
#pragma unroll
    for (int off = 1; off < 64; off <<= 1) rv += __shfl_xor(rv, off, 64);
    rterm = rv / (float)NN;
  }

  if (lane == 0) ws2[g] = term / (float)DD + rterm;
}

__global__ __launch_bounds__(256) void spl_pass3(const float* __restrict__ ws2,
                                                 float* __restrict__ out) {
  const int tid = threadIdx.x;
  float acc = ws2[tid];
#pragma unroll
  for (int off = 1; off < 64; off <<= 1) acc += __shfl_xor(acc, off, 64);

  __shared__ float wsum[4];
  if ((tid & 63) == 0) wsum[tid >> 6] = acc;
  __syncthreads();
  if (tid == 0) {
    out[0] = -(wsum[0] + wsum[1] + wsum[2] + wsum[3]) / (float)BB;
  }
}

extern "C" void kernel_launch(void* const* d_in, const int* in_sizes, int n_in,
                              void* d_out, int out_size, void* d_ws, size_t ws_size,
                              hipStream_t stream) {
  const float* x = (const float*)d_in[0];
  const float* r = (const float*)d_in[1];
  float* out = (float*)d_out;
  float* ws = (float*)d_ws;

  (void)in_sizes; (void)n_in; (void)out_size; (void)ws_size;

  spl_pass1<<<BB * BPB, 256, 0, stream>>>(x, r, ws);
  spl_pass2<<<256, 64, 0, stream>>>(ws, ws + WS_W2);
  spl_pass3<<<1, 256, 0, stream>>>(ws + WS_W2, out);
}

// Round 12
// 120.853 us; speedup vs baseline: 4.7227x; 4.7227x over previous
//
#include <hip/hip_runtime.h>
#include <math.h>

// SPLFullLoss: x, ref f32[B=32, N=4096, D=512] -> scalar
//   a = -(1/(N*B)) * sum_rows Sxr/(max(sqrt(Sxx),eps)*max(sqrt(Srr),eps))  (rows along D)
//   b = -(1/(D*B)) * sum_cols Sxr/(max(sqrt(Sxx),eps)*max(sqrt(Srr),eps))  (cols along N)
// R12 = R9 (champion, 124.9 us): R4 streaming body + atomic-free epilogue.
// pass1 stores column-partials to unique per-block slots (coalesced stores),
// pass2 (256 x 1-wave) reduces across the 64 blocks of each batch,
// pass3 (1 block) combines 256 partials into the scalar.
// Evidence from R1-R11: delivered read BW is pinned at ~4.5 TB/s (~6.3 B/cyc/CU)
// across 8 independent structures (occupancy, MLP, access pattern, nt, DMA-LDS)
// -> per-CU read-path hardware cap; pass1 runs at it.

#define BB 32
#define NN 4096
#define DD 512

static constexpr float EPS = 1e-12f;
static constexpr int BPB   = 64;          // blocks per batch
static constexpr int RPB   = NN / BPB;    // 64 rows per block
static constexpr int NWAVE = 4;           // 256 threads
static constexpr int RPW   = RPB / NWAVE; // 16 rows per wave
static constexpr int SUB   = 4;           // rows per super-iteration
static constexpr int NSUB  = RPW / SUB;   // 4

// ws layout (floats):
//   P[2048 blocks][1600]: [0,512) cxx | [512,1024) crr | [1024,1536) cxr | [1536] rowacc
//   ws2[256] at offset 2048*1600: per-(batch, d-slice) terms (slice 0 also carries row term)
static constexpr size_t S1     = 1600;                 // padded block-slot stride
static constexpr size_t WS_W2  = (size_t)2048 * S1;
static constexpr size_t WS_FLOATS = WS_W2 + 256;

__global__ __launch_bounds__(256, 4) void spl_pass1(
    const float* __restrict__ x, const float* __restrict__ r, float* __restrict__ ws) {
  // col exchange buffer, half-D at a time: [wave][m][256] floats = 12 KiB
  __shared__ float lds[NWAVE][3][DD / 2];
  __shared__ float ldsrow[NWAVE];

  const int tid  = threadIdx.x;
  const int wave = tid >> 6;
  const int lane = tid & 63;
  const int blk  = blockIdx.x;
  const int b    = blk / BPB;
  const int bib  = blk % BPB;
  const int n0   = bib * RPB + wave * RPW;

  float cxx[8], crr[8], cxr[8];
#pragma unroll
  for (int j = 0; j < 8; ++j) { cxx[j] = 0.f; crr[j] = 0.f; cxr[j] = 0.f; }
  float rowacc = 0.f;

  const size_t base = (size_t)b * NN * DD + (size_t)n0 * DD;
  const float* xb = x + base;
  const float* rb = r + base;

#pragma unroll 1
  for (int s = 0; s < NSUB; ++s) {
    // ---- phase 1: issue all 16 loads for 4 rows
    float4 xd[SUB][2], rd[SUB][2];
#pragma unroll
    for (int rr = 0; rr < SUB; ++rr) {
      const float4* xp = (const float4*)(xb + (size_t)(s * SUB + rr) * DD);
      const float4* rp = (const float4*)(rb + (size_t)(s * SUB + rr) * DD);
      xd[rr][0] = xp[lane];
      xd[rr][1] = xp[lane + 64];
      rd[rr][0] = rp[lane];
      rd[rr][1] = rp[lane + 64];
    }

    // ---- phase 2: FMAs (row partials + column accumulators)
    float sxx[SUB], srr[SUB], sxr[SUB];
#pragma unroll
    for (int rr = 0; rr < SUB; ++rr) {
      sxx[rr] = 0.f; srr[rr] = 0.f; sxr[rr] = 0.f;
#pragma unroll
      for (int k = 0; k < 2; ++k) {
        const float xs[4] = {xd[rr][k].x, xd[rr][k].y, xd[rr][k].z, xd[rr][k].w};
        const float rs[4] = {rd[rr][k].x, rd[rr][k].y, rd[rr][k].z, rd[rr][k].w};
#pragma unroll
        for (int j = 0; j < 4; ++j) {
          const float pxx = xs[j] * xs[j];
          const float prr = rs[j] * rs[j];
          const float pxr = xs[j] * rs[j];
          sxx[rr] += pxx; srr[rr] += prr; sxr[rr] += pxr;
          cxx[k * 4 + j] += pxx; crr[k * 4 + j] += prr; cxr[k * 4 + j] += pxr;
        }
      }
    }

    // ---- phase 3: 12 independent butterfly chains, interleaved
#pragma unroll
    for (int off = 1; off < 64; off <<= 1) {
#pragma unroll
      for (int rr = 0; rr < SUB; ++rr) {
        sxx[rr] += __shfl_xor(sxx[rr], off, 64);
        srr[rr] += __shfl_xor(srr[rr], off, 64);
        sxr[rr] += __shfl_xor(sxr[rr], off, 64);
      }
    }
#pragma unroll
    for (int rr = 0; rr < SUB; ++rr) {
      const float nx = fmaxf(sqrtf(sxx[rr]), EPS);
      const float nr = fmaxf(sqrtf(srr[rr]), EPS);
      rowacc += sxr[rr] / (nx * nr);
    }
  }

  if (lane == 0) ldsrow[wave] = rowacc;

  float* P = ws + (size_t)blk * S1;

  // ---- column exchange, half 0: d in [0,256), reg slots 0..3
  __syncthreads();
  {
    float4* cb = (float4*)&lds[0][0][0];  // [wave*3+m][64] float4s
#pragma unroll
    for (int m = 0; m < 3; ++m) {
      const float* c = (m == 0) ? cxx : (m == 1) ? crr : cxr;
      cb[(wave * 3 + m) * 64 + lane] = make_float4(c[0], c[1], c[2], c[3]);
    }
  }
  __syncthreads();
  for (int i = tid; i < 768; i += 256) {
    const int m = i >> 8;
    const int d = i & 255;
    P[m * 512 + d] = lds[0][m][d] + lds[1][m][d] + lds[2][m][d] + lds[3][m][d];
  }

  // ---- column exchange, half 1: d in [256,512), reg slots 4..7
  __syncthreads();
  {
    float4* cb = (float4*)&lds[0][0][0];
#pragma unroll
    for (int m = 0; m < 3; ++m) {
      const float* c = (m == 0) ? cxx : (m == 1) ? crr : cxr;
      cb[(wave * 3 + m) * 64 + lane] = make_float4(c[4], c[5], c[6], c[7]);
    }
  }
  __syncthreads();
  for (int i = tid; i < 768; i += 256) {
    const int m = i >> 8;
    const int d = i & 255;
    P[m * 512 + 256 + d] = lds[0][m][d] + lds[1][m][d] + lds[2][m][d] + lds[3][m][d];
  }

  if (tid == 0) {
    P[1536] = ldsrow[0] + ldsrow[1] + ldsrow[2] + ldsrow[3];
  }
}

// 256 blocks x 64 threads: block g handles batch b=g/8, d-slice (g%8)*64..+64.
// Reduces the 64 per-block partials; slice 0 also reduces the 64 row partials.
__global__ __launch_bounds__(64, 8) void spl_pass2(const float* __restrict__ ws,
                                                   float* __restrict__ ws2) {
  const int lane = threadIdx.x;
  const int g    = blockIdx.x;
  const int b    = g >> 3;
  const int d    = (g & 7) * 64 + lane;

  float sxx = 0.f, srr = 0.f, sxr = 0.f;
  const float* Pb = ws + (size_t)(b * BPB) * S1;
#pragma unroll 4
  for (int bib = 0; bib < BPB; ++bib) {
    const float* P = Pb + (size_t)bib * S1;
    sxx += P[d];
    srr += P[512 + d];
    sxr += P[1024 + d];
  }
  const float nx = fmaxf(sqrtf(sxx), EPS);
  const float nr = fmaxf(sqrtf(srr), EPS);
  float term = sxr / (nx * nr);   // per-d column term
#pragma unroll
  for (int off = 1; off < 64; off <<= 1) term += __shfl_xor(term, off, 64);

  float rterm = 0.f;
  if ((g & 7) == 0) {
    float rv = Pb[(size_t)lane * S1 + 1536];  // one row-partial per lane
#pragma unroll
    for (int off = 1; off < 64; off <<= 1) rv += __shfl_xor(rv, off, 64);
    rterm = rv / (float)NN;
  }

  if (lane == 0) ws2[g] = term / (float)DD + rterm;
}

__global__ __launch_bounds__(256) void spl_pass3(const float* __restrict__ ws2,
                                                 float* __restrict__ out) {
  const int tid = threadIdx.x;
  float acc = ws2[tid];
#pragma unroll
  for (int off = 1; off < 64; off <<= 1) acc += __shfl_xor(acc, off, 64);

  __shared__ float wsum[4];
  if ((tid & 63) == 0) wsum[tid >> 6] = acc;
  __syncthreads();
  if (tid == 0) {
    out[0] = -(wsum[0] + wsum[1] + wsum[2] + wsum[3]) / (float)BB;
  }
}

extern "C" void kernel_launch(void* const* d_in, const int* in_sizes, int n_in,
                              void* d_out, int out_size, void* d_ws, size_t ws_size,
                              hipStream_t stream) {
  const float* x = (const float*)d_in[0];
  const float* r = (const float*)d_in[1];
  float* out = (float*)d_out;
  float* ws = (float*)d_ws;

  (void)in_sizes; (void)n_in; (void)out_size; (void)ws_size;

  spl_pass1<<<BB * BPB, 256, 0, stream>>>(x, r, ws);
  spl_pass2<<<256, 64, 0, stream>>>(ws, ws + WS_W2);
  spl_pass3<<<1, 256, 0, stream>>>(ws + WS_W2, out);
}